// Round 11
// baseline (121.930 us; speedup 1.0000x reference)
//
#include <hip/hip_runtime.h>
#include <hip/hip_bf16.h>

#define NROWS 8192
#define DIM 512

typedef int   i32x4 __attribute__((ext_vector_type(4)));
typedef int   i32x8 __attribute__((ext_vector_type(8)));
typedef float f32x4 __attribute__((ext_vector_type(4)));

#define FP8_SCALE_1 0x7f7f7f7f    // E8M0 127 = 2^0 in all 4 bytes

__device__ __forceinline__ void gld_lds16(const void* g, void* l) {
  __builtin_amdgcn_global_load_lds(
      (__attribute__((address_space(1))) unsigned int*)(g),
      (__attribute__((address_space(3))) unsigned int*)(l),
      16, 0, 0);
}

// ---------- Phase 1: normalize rows -> fp8 e4m3; diag logits in fp32 ----------
__global__ __launch_bounds__(128) void prep_k(
    const float* __restrict__ q, const float* __restrict__ p,
    unsigned int* __restrict__ qh, unsigned int* __restrict__ ph,
    float* __restrict__ diag) {
  const int i = blockIdx.x;
  const int t = threadIdx.x;
  const int lane = t & 63, wid = t >> 6;
  const float4 qv = ((const float4*)(q + (size_t)i * DIM))[t];
  const float4 pv = ((const float4*)(p + (size_t)i * DIM))[t];
  float ssq = qv.x*qv.x + qv.y*qv.y + qv.z*qv.z + qv.w*qv.w;
  float ssp = pv.x*pv.x + pv.y*pv.y + pv.z*pv.z + pv.w*pv.w;
  float dt  = qv.x*pv.x + qv.y*pv.y + qv.z*pv.z + qv.w*pv.w;
  #pragma unroll
  for (int m = 1; m < 64; m <<= 1) {
    ssq += __shfl_xor(ssq, m, 64);
    ssp += __shfl_xor(ssp, m, 64);
    dt  += __shfl_xor(dt,  m, 64);
  }
  __shared__ float red[3][2];
  if (lane == 0) { red[0][wid] = ssq; red[1][wid] = ssp; red[2][wid] = dt; }
  __syncthreads();
  ssq = red[0][0] + red[0][1];
  ssp = red[1][0] + red[1][1];
  dt  = red[2][0] + red[2][1];
  const float invq = 1.0f / fmaxf(sqrtf(ssq), 1e-8f);
  const float invp = 1.0f / fmaxf(sqrtf(ssp), 1e-8f);
  int rq = 0, rp = 0;
  rq = __builtin_amdgcn_cvt_pk_fp8_f32(qv.x * invq, qv.y * invq, rq, false);
  rq = __builtin_amdgcn_cvt_pk_fp8_f32(qv.z * invq, qv.w * invq, rq, true);
  rp = __builtin_amdgcn_cvt_pk_fp8_f32(pv.x * invp, pv.y * invp, rp, false);
  rp = __builtin_amdgcn_cvt_pk_fp8_f32(pv.z * invp, pv.w * invp, rp, true);
  qh[i * 128 + t] = (unsigned int)rq;
  ph[i * 128 + t] = (unsigned int)rp;
  if (t == 0) diag[i] = dt * invq * invp * 20.0f;
}

// ---------- Phase 2: MX-fp8 GEMM, A-panel in REGISTERS ----------
// 256 persistent blocks (1/CU), 512 thr = 8 waves (2M x 4N), 64x64 out/wave.
// Block owns fixed 128-row A panel: per lane 16 frags x 32B = 128 VGPR,
// loaded from global ONCE (no A staging/LDS/lgkm in the loop). Per K-iter
// only B: 32KB staged (gld_lds), 8 ds_read_b128/wave. MFMA per SIMD (1104cy)
// now dominates LDS (768cy/CU); compiler's progressive lgkmcnt lets MFMA
// start after bf[0] lands, hiding remaining reads. K-loop fully unrolled so
// a[kt][mf] is statically indexed (no scratch). Buffer race: sb(it) readers
// retired (lgkm) before their it-1 barrier; one vmcnt(0)+barrier per iter.
// Grid: colstrip = b&3 (2048 cols; XCD pair shares 1MB L2-hot B-strip),
// rowpanel = b>>2; 8 output tiles (128x256) x 4 K-iters each.
__device__ __forceinline__ i32x8 rd32(const char* base, int c0, int sw) {
  const i32x4 lo = *(const i32x4*)(base + ((c0     ) ^ sw));
  const i32x4 hi = *(const i32x4*)(base + ((c0 + 16) ^ sw));
  return __builtin_shufflevector(lo, hi, 0, 1, 2, 3, 4, 5, 6, 7);
}
__device__ __forceinline__ i32x8 ldg32(const char* g) {
  const i32x4 lo = *(const i32x4*)(g);
  const i32x4 hi = *(const i32x4*)(g + 16);
  return __builtin_shufflevector(lo, hi, 0, 1, 2, 3, 4, 5, 6, 7);
}
// stage one 256-row x 128B B K-tile (4 gld_lds per thread, 512 threads)
__device__ __forceinline__ void stage_B(const char* __restrict__ g, char* dstb,
                                        int rowbase, int tid, int kb) {
  #pragma unroll
  for (int j = 0; j < 4; ++j) {
    const int idx = j * 512 + tid;
    const int rl = idx >> 3;
    const int scb = ((idx & 7) << 4) ^ ((rl & 7) << 4);
    gld_lds16(g + (size_t)(rowbase + rl) * 512 + kb + scb, dstb + idx * 16);
  }
}

__global__ __launch_bounds__(512, 2) void gemm_lse_k(
    const unsigned int* __restrict__ qh, const unsigned int* __restrict__ ph,
    float* __restrict__ partial) {
  __shared__ __attribute__((aligned(16))) char lds[67584];  // 2x32KB B + 2KB psum
  const int tid = threadIdx.x;
  const int lane = tid & 63, wid = tid >> 6;
  const int wr = wid >> 2, wc = wid & 3;        // 2M x 4N wave grid
  const int l15 = lane & 15, l4 = lane >> 4;
  const int sw = (l15 & 7) << 4;
  const int c0 = l4 * 32;
  const int b = blockIdx.x;
  const int colstrip = b & 3;
  const int bm = (b >> 2) * 128;
  const int bnbase = colstrip * 2048;
  const char* qh8 = (const char*)qh;
  const char* ph8 = (const char*)ph;
  float* psum = (float*)(lds + 65536);          // [4][128]
  const int bOff = (wc * 64 + l15) * 128;       // + nf*2048

  // ---- A panel -> registers (16 frags x 32B/lane = 128 VGPR), once ----
  i32x8 a[4][4];                                // [kt][mf], static idx only
  #pragma unroll
  for (int kt = 0; kt < 4; ++kt)
    #pragma unroll
    for (int mf = 0; mf < 4; ++mf)
      a[kt][mf] = ldg32(qh8 +
          (size_t)(bm + wr * 64 + mf * 16 + l15) * 512 + kt * 128 + c0);

  f32x4 acc[4][4] = {};

  // Prologue: stage B(tile0, kt0) -> buf0, drain, barrier.
  stage_B(ph8, lds, bnbase, tid, 0);
  asm volatile("s_waitcnt vmcnt(0)" ::: "memory");
  __builtin_amdgcn_s_barrier();

  #pragma unroll 1
  for (int t = 0; t < 8; ++t) {
    #pragma unroll
    for (int kt = 0; kt < 4; ++kt) {
      const char* rb = lds + (kt & 1) * 32768;
      char* sb = lds + ((kt + 1) & 1) * 32768;
      const int ktn = (kt + 1) & 3;
      const int tn = (kt == 3) ? t + 1 : t;
      i32x8 bf[4];
      #pragma unroll
      for (int nf = 0; nf < 4; ++nf)
        bf[nf] = rd32(rb + bOff + nf * 2048, c0, sw);
      if (!(t == 7 && kt == 3))
        stage_B(ph8, sb, bnbase + (tn & 7) * 256, tid, ktn * 128);
      __builtin_amdgcn_s_setprio(1);
      #pragma unroll
      for (int mf = 0; mf < 4; ++mf)
        #pragma unroll
        for (int nf = 0; nf < 4; ++nf)
          acc[mf][nf] = __builtin_amdgcn_mfma_scale_f32_16x16x128_f8f6f4(
              a[kt][mf], bf[nf], acc[mf][nf], 0, 0,
              0, FP8_SCALE_1, 0, FP8_SCALE_1);
      __builtin_amdgcn_s_setprio(0);
      asm volatile("s_waitcnt vmcnt(0)" ::: "memory");
      __builtin_amdgcn_s_barrier();
    }

    // ---- flush output tile t: exp(20c-20) + row-sum over 256 cols ----
    #pragma unroll
    for (int mf = 0; mf < 4; ++mf) {
      #pragma unroll
      for (int r = 0; r < 4; ++r) {
        float s = 0.0f;
        #pragma unroll
        for (int nf = 0; nf < 4; ++nf)
          s += __expf(acc[mf][nf][r] * 20.0f - 20.0f);
        s += __shfl_xor(s, 1, 64);
        s += __shfl_xor(s, 2, 64);
        s += __shfl_xor(s, 4, 64);
        s += __shfl_xor(s, 8, 64);
        if (l15 == 0)
          psum[wc * 128 + wr * 64 + mf * 16 + l4 * 4 + r] = s;
      }
    }
    asm volatile("s_waitcnt lgkmcnt(0)" ::: "memory");
    __builtin_amdgcn_s_barrier();
    if (tid < 128) {
      float s = psum[tid] + psum[128 + tid] + psum[256 + tid] + psum[384 + tid];
      partial[(size_t)(bm + tid) * 32 + colstrip * 8 + t] = s;
    }
    #pragma unroll
    for (int mf = 0; mf < 4; ++mf)
      #pragma unroll
      for (int nf = 0; nf < 4; ++nf)
        acc[mf][nf] = f32x4{0.0f, 0.0f, 0.0f, 0.0f};
  }
}

// ---------- Phase 3a: per-row loss ----------
__global__ __launch_bounds__(256) void rowloss_k(
    const float* __restrict__ partial, const float* __restrict__ diag,
    float* __restrict__ rowloss) {
  const int i = blockIdx.x * 256 + threadIdx.x;
  const float4* pr = (const float4*)(partial + (size_t)i * 32);
  float s = 0.0f;
  #pragma unroll
  for (int c = 0; c < 8; ++c) {
    const float4 v = pr[c];
    s += v.x + v.y + v.z + v.w;
  }
  rowloss[i] = __logf(s) + 20.0f - diag[i];
}

// ---------- Phase 3b: mean ----------
__global__ __launch_bounds__(1024) void final_k(
    const float* __restrict__ rowloss, float* __restrict__ out) {
  const int t = threadIdx.x;
  float s = 0.0f;
  #pragma unroll
  for (int j = 0; j < 8; ++j) s += rowloss[t + j * 1024];
  #pragma unroll
  for (int m = 1; m < 64; m <<= 1) s += __shfl_xor(s, m, 64);
  __shared__ float red[16];
  if ((t & 63) == 0) red[t >> 6] = s;
  __syncthreads();
  if (t == 0) {
    float acc = 0.0f;
    #pragma unroll
    for (int w = 0; w < 16; ++w) acc += red[w];
    out[0] = acc * (1.0f / (float)NROWS);
  }
}

extern "C" void kernel_launch(void* const* d_in, const int* in_sizes, int n_in,
                              void* d_out, int out_size, void* d_ws, size_t ws_size,
                              hipStream_t stream) {
  const float* q = (const float*)d_in[0];
  const float* p = (const float*)d_in[1];
  char* w = (char*)d_ws;
  unsigned int* qh = (unsigned int*)w;                        // 4 MB fp8
  unsigned int* ph = (unsigned int*)(w + 4194304);            // 4 MB fp8
  float* partial    = (float*)(w + 8388608);                  // 1 MB [8192][32]
  float* diag       = (float*)(w + 9437184);                  // 32 KB
  float* rowloss    = (float*)(w + 9437184 + 32768);          // 32 KB
  float* out = (float*)d_out;

  prep_k<<<NROWS, 128, 0, stream>>>(q, p, qh, ph, diag);
  gemm_lse_k<<<256, 512, 0, stream>>>(qh, ph, partial);
  rowloss_k<<<NROWS / 256, 256, 0, stream>>>(partial, diag, rowloss);
  final_k<<<1, 1024, 0, stream>>>(rowloss, out);
}

// Round 13
// 70.638 us; speedup vs baseline: 1.7261x; 1.7261x over previous
//
#include <hip/hip_runtime.h>
#include <hip/hip_bf16.h>

#define NROWS 8192
#define DIM 512
#define BM 256
#define BN 256

typedef int   i32x4 __attribute__((ext_vector_type(4)));
typedef int   i32x8 __attribute__((ext_vector_type(8)));
typedef float f32x4 __attribute__((ext_vector_type(4)));

#define FP8_SCALE_1 0x7f7f7f7f   // E8M0 127 = 2^0 in all 4 bytes

__device__ __forceinline__ void gld_lds16(const void* g, void* l) {
  __builtin_amdgcn_global_load_lds(
      (__attribute__((address_space(1))) unsigned int*)(g),
      (__attribute__((address_space(3))) unsigned int*)(l),
      16, 0, 0);
}

// ---------- Phase 1: normalize rows -> fp8 e4m3; diag logits in fp32 ----------
__global__ __launch_bounds__(128) void prep_k(
    const float* __restrict__ q, const float* __restrict__ p,
    unsigned int* __restrict__ qh, unsigned int* __restrict__ ph,
    float* __restrict__ diag) {
  const int i = blockIdx.x;
  const int t = threadIdx.x;
  const int lane = t & 63, wid = t >> 6;
  const float4 qv = ((const float4*)(q + (size_t)i * DIM))[t];
  const float4 pv = ((const float4*)(p + (size_t)i * DIM))[t];
  float ssq = qv.x*qv.x + qv.y*qv.y + qv.z*qv.z + qv.w*qv.w;
  float ssp = pv.x*pv.x + pv.y*pv.y + pv.z*pv.z + pv.w*pv.w;
  float dt  = qv.x*pv.x + qv.y*pv.y + qv.z*pv.z + qv.w*pv.w;
  #pragma unroll
  for (int m = 1; m < 64; m <<= 1) {
    ssq += __shfl_xor(ssq, m, 64);
    ssp += __shfl_xor(ssp, m, 64);
    dt  += __shfl_xor(dt,  m, 64);
  }
  __shared__ float red[3][2];
  if (lane == 0) { red[0][wid] = ssq; red[1][wid] = ssp; red[2][wid] = dt; }
  __syncthreads();
  ssq = red[0][0] + red[0][1];
  ssp = red[1][0] + red[1][1];
  dt  = red[2][0] + red[2][1];
  const float invq = 1.0f / fmaxf(sqrtf(ssq), 1e-8f);
  const float invp = 1.0f / fmaxf(sqrtf(ssp), 1e-8f);
  int rq = 0, rp = 0;
  rq = __builtin_amdgcn_cvt_pk_fp8_f32(qv.x * invq, qv.y * invq, rq, false);
  rq = __builtin_amdgcn_cvt_pk_fp8_f32(qv.z * invq, qv.w * invq, rq, true);
  rp = __builtin_amdgcn_cvt_pk_fp8_f32(pv.x * invp, pv.y * invp, rp, false);
  rp = __builtin_amdgcn_cvt_pk_fp8_f32(pv.z * invp, pv.w * invp, rp, true);
  qh[i * 128 + t] = (unsigned int)rq;
  ph[i * 128 + t] = (unsigned int)rp;
  if (t == 0) diag[i] = dt * invq * invp * 20.0f;
}

// ---------- Phase 2: persistent MX-fp8 GEMM, L2-resident XCD mapping ----------
// IDENTICAL to the r9 61.4us kernel except the block->(bm,bn) map:
// XCD g=b&7 owns rowgrp=g&3 (8 A panels, 1MB) x colgrp=g>>2 (16 B panels, 2MB)
// -> 3MB unique per XCD, fits 4MB L2. Block j=b>>3: bm panel = rowgrp*8+(j&7)
// (shared by 4 blocks), bn-set = colgrp*16+(j>>3)*4 (shared by 8 blocks).
// All A re-reads (4x/block) and B sharing become L2 hits; the per-iter
// vmcnt(0) drain waits on L2 (~500cy) instead of L3/HBM (~4000cy).
__device__ __forceinline__ i32x8 rd32(const char* base, int c0, int sw) {
  const i32x4 lo = *(const i32x4*)(base + ((c0     ) ^ sw));
  const i32x4 hi = *(const i32x4*)(base + ((c0 + 16) ^ sw));
  return __builtin_shufflevector(lo, hi, 0, 1, 2, 3, 4, 5, 6, 7);
}
__device__ __forceinline__ void stage_half(const char* __restrict__ g, char* dstb,
                                           int rowbase, int h, int tid, int kb) {
  #pragma unroll
  for (int j = 0; j < 2; ++j) {
    const int idx = j * 512 + tid;
    const int rl = idx >> 3;
    const int scb = ((idx & 7) << 4) ^ ((rl & 7) << 4);
    gld_lds16(g + (size_t)(rowbase + h * 128 + rl) * 512 + kb + scb,
              dstb + h * 16384 + idx * 16);
  }
}

#define MFMA_Q(AF, BF, Q, QB)                                                 \
  __builtin_amdgcn_s_setprio(1);                                              \
  _Pragma("unroll") for (int mf = 0; mf < 4; ++mf)                            \
    _Pragma("unroll") for (int nf = 0; nf < 2; ++nf)                          \
      acc[Q * 4 + mf][QB * 2 + nf] =                                          \
          __builtin_amdgcn_mfma_scale_f32_16x16x128_f8f6f4(                   \
              AF[mf], BF[nf], acc[Q * 4 + mf][QB * 2 + nf], 0, 0,             \
              0, FP8_SCALE_1, 0, FP8_SCALE_1);                                \
  __builtin_amdgcn_s_setprio(0);

__global__ __launch_bounds__(512, 2) void gemm_lse_k(
    const unsigned int* __restrict__ qh, const unsigned int* __restrict__ ph,
    float* __restrict__ partial) {
  __shared__ __attribute__((aligned(16))) char lds[135168];  // 2x64KB + 4KB psum
  const int tid = threadIdx.x;
  const int lane = tid & 63, wid = tid >> 6;
  const int wr = wid >> 2, wc = wid & 3;
  const int l15 = lane & 15, l4 = lane >> 4;
  const int sw = (l15 & 7) << 4;
  const int c0 = l4 * 32;
  const int b = blockIdx.x;
  const int g = b & 7;                    // XCD (round-robin dispatch)
  const int j = b >> 3;                   // 0..31 within XCD
  const int rowgrp = g & 3, colgrp = g >> 2;
  const int bm = (rowgrp * 8 + (j & 7)) * BM;        // A panel (4 blocks share)
  const int bnset = colgrp * 16 + (j >> 3) * 4;      // 4 bn panels (8 share)
  const char* qh8 = (const char*)qh;
  const char* ph8 = (const char*)ph;
  float* psum = (float*)(lds + 131072);
  const int aOff = wr * 16384 + l15 * 128;
  const int bOff = 32768 + (wc >> 1) * 16384 +
                   ((wc & 1) * 64 + l15) * 128;

  f32x4 acc[8][4] = {};
  i32x8 af0[4], af1[4], bf0[2], bf1[2];

  // Prologue: stage tile 0 (bn = bnset, k-tile 0), drain, barrier.
  {
    const int bn0 = bnset * BN;
    stage_half(qh8, lds, bm, 0, tid, 0);
    stage_half(ph8, lds + 32768, bn0, 0, tid, 0);
    stage_half(ph8, lds + 32768, bn0, 1, tid, 0);
    stage_half(qh8, lds, bm, 1, tid, 0);
    asm volatile("s_waitcnt vmcnt(0)" ::: "memory");
    __builtin_amdgcn_s_barrier();
  }

  #pragma unroll 1
  for (int tt = 0; tt < 16; ++tt) {
    const char* rb = lds + (tt & 1) * 65536;
    char* sbA = lds + ((tt + 1) & 1) * 65536;
    char* sbB = sbA + 32768;
    const int ttn = tt + 1;
    const int kbn = (ttn & 3) * 128;                     // next K-tile byte offset
    const int bnn = (bnset + ((ttn >> 2) & 3)) * BN;     // next tile's bn
    const bool st = (tt < 15);

    // front-load reads (16 + 8 ds_read_b128)
    #pragma unroll
    for (int mf = 0; mf < 4; ++mf)
      af0[mf] = rd32(rb + aOff + mf * 2048, c0, sw);
    #pragma unroll
    for (int nf = 0; nf < 2; ++nf)
      bf0[nf] = rd32(rb + bOff + nf * 2048, c0, sw);
    #pragma unroll
    for (int nf = 0; nf < 2; ++nf)
      bf1[nf] = rd32(rb + bOff + 4096 + nf * 2048, c0, sw);
    if (st) {
      stage_half(qh8, sbA, bm, 0, tid, kbn);
      stage_half(ph8, sbB, bnn, 0, tid, kbn);
    }
    MFMA_Q(af0, bf0, 0, 0);
    #pragma unroll
    for (int mf = 0; mf < 4; ++mf)
      af1[mf] = rd32(rb + aOff + 8192 + mf * 2048, c0, sw);
    MFMA_Q(af0, bf1, 0, 1);
    if (st) {
      stage_half(ph8, sbB, bnn, 1, tid, kbn);
      stage_half(qh8, sbA, bm, 1, tid, kbn);
    }
    MFMA_Q(af1, bf1, 1, 1);
    MFMA_Q(af1, bf0, 1, 0);

    asm volatile("s_waitcnt vmcnt(0)" ::: "memory");  // stages landed (issued early)
    __builtin_amdgcn_s_barrier();

    if ((tt & 3) == 3) {
      // ---- flush output tile (tt>>2): exp(20c-20) + row-sum + store ----
      const int bxc = bnset + (tt >> 2);
      #pragma unroll
      for (int am = 0; am < 8; ++am) {
        #pragma unroll
        for (int r = 0; r < 4; ++r) {
          float s = 0.0f;
          #pragma unroll
          for (int nb = 0; nb < 4; ++nb)
            s += __expf(acc[am][nb][r] * 20.0f - 20.0f);
          s += __shfl_xor(s, 1, 64);
          s += __shfl_xor(s, 2, 64);
          s += __shfl_xor(s, 4, 64);
          s += __shfl_xor(s, 8, 64);
          if (l15 == 0)
            psum[wc * 256 + wr * 128 + am * 16 + l4 * 4 + r] = s;
        }
      }
      asm volatile("s_waitcnt lgkmcnt(0)" ::: "memory");
      __builtin_amdgcn_s_barrier();
      if (tid < 256) {
        float s = psum[tid] + psum[256 + tid] + psum[512 + tid] + psum[768 + tid];
        partial[(size_t)(bm + tid) * 32 + bxc] = s;
      }
      #pragma unroll
      for (int am = 0; am < 8; ++am)
        #pragma unroll
        for (int nb = 0; nb < 4; ++nb)
          acc[am][nb] = f32x4{0.0f, 0.0f, 0.0f, 0.0f};
    }
  }
}

// ---------- Phase 3a: per-row loss ----------
__global__ __launch_bounds__(256) void rowloss_k(
    const float* __restrict__ partial, const float* __restrict__ diag,
    float* __restrict__ rowloss) {
  const int i = blockIdx.x * 256 + threadIdx.x;
  const float4* pr = (const float4*)(partial + (size_t)i * 32);
  float s = 0.0f;
  #pragma unroll
  for (int c = 0; c < 8; ++c) {
    const float4 v = pr[c];
    s += v.x + v.y + v.z + v.w;
  }
  rowloss[i] = __logf(s) + 20.0f - diag[i];
}

// ---------- Phase 3b: mean ----------
__global__ __launch_bounds__(1024) void final_k(
    const float* __restrict__ rowloss, float* __restrict__ out) {
  const int t = threadIdx.x;
  float s = 0.0f;
  #pragma unroll
  for (int j = 0; j < 8; ++j) s += rowloss[t + j * 1024];
  #pragma unroll
  for (int m = 1; m < 64; m <<= 1) s += __shfl_xor(s, m, 64);
  __shared__ float red[16];
  if ((t & 63) == 0) red[t >> 6] = s;
  __syncthreads();
  if (t == 0) {
    float acc = 0.0f;
    #pragma unroll
    for (int w = 0; w < 16; ++w) acc += red[w];
    out[0] = acc * (1.0f / (float)NROWS);
  }
}

extern "C" void kernel_launch(void* const* d_in, const int* in_sizes, int n_in,
                              void* d_out, int out_size, void* d_ws, size_t ws_size,
                              hipStream_t stream) {
  const float* q = (const float*)d_in[0];
  const float* p = (const float*)d_in[1];
  char* w = (char*)d_ws;
  unsigned int* qh = (unsigned int*)w;                        // 4 MB fp8
  unsigned int* ph = (unsigned int*)(w + 4194304);            // 4 MB fp8
  float* partial    = (float*)(w + 8388608);                  // 1 MB [8192][32]
  float* diag       = (float*)(w + 9437184);                  // 32 KB
  float* rowloss    = (float*)(w + 9437184 + 32768);          // 32 KB
  float* out = (float*)d_out;

  prep_k<<<NROWS, 128, 0, stream>>>(q, p, qh, ph, diag);
  gemm_lse_k<<<256, 512, 0, stream>>>(qh, ph, partial);
  rowloss_k<<<NROWS / 256, 256, 0, stream>>>(partial, diag, rowloss);
  final_k<<<1, 1024, 0, stream>>>(rowloss, out);
}

// Round 15
// 57.910 us; speedup vs baseline: 2.1055x; 1.2198x over previous
//
#include <hip/hip_runtime.h>
#include <hip/hip_bf16.h>

#define NROWS 8192
#define DIM 512
#define BM 256
#define BN 256

typedef int   i32x4 __attribute__((ext_vector_type(4)));
typedef int   i32x8 __attribute__((ext_vector_type(8)));
typedef float f32x4 __attribute__((ext_vector_type(4)));

#define FP8_SCALE_1 0x7f7f7f7f   // E8M0 127 = 2^0 in all 4 bytes

__device__ __forceinline__ void gld_lds16(const void* g, void* l) {
  __builtin_amdgcn_global_load_lds(
      (__attribute__((address_space(1))) unsigned int*)(g),
      (__attribute__((address_space(3))) unsigned int*)(l),
      16, 0, 0);
}

// ---------- Phase 1: normalize rows -> fp8 e4m3; diag logits in fp32 ----------
__global__ __launch_bounds__(128) void prep_k(
    const float* __restrict__ q, const float* __restrict__ p,
    unsigned int* __restrict__ qh, unsigned int* __restrict__ ph,
    float* __restrict__ diag) {
  const int i = blockIdx.x;
  const int t = threadIdx.x;
  const int lane = t & 63, wid = t >> 6;
  const float4 qv = ((const float4*)(q + (size_t)i * DIM))[t];
  const float4 pv = ((const float4*)(p + (size_t)i * DIM))[t];
  float ssq = qv.x*qv.x + qv.y*qv.y + qv.z*qv.z + qv.w*qv.w;
  float ssp = pv.x*pv.x + pv.y*pv.y + pv.z*pv.z + pv.w*pv.w;
  float dt  = qv.x*pv.x + qv.y*pv.y + qv.z*pv.z + qv.w*pv.w;
  #pragma unroll
  for (int m = 1; m < 64; m <<= 1) {
    ssq += __shfl_xor(ssq, m, 64);
    ssp += __shfl_xor(ssp, m, 64);
    dt  += __shfl_xor(dt,  m, 64);
  }
  __shared__ float red[3][2];
  if (lane == 0) { red[0][wid] = ssq; red[1][wid] = ssp; red[2][wid] = dt; }
  __syncthreads();
  ssq = red[0][0] + red[0][1];
  ssp = red[1][0] + red[1][1];
  dt  = red[2][0] + red[2][1];
  const float invq = 1.0f / fmaxf(sqrtf(ssq), 1e-8f);
  const float invp = 1.0f / fmaxf(sqrtf(ssp), 1e-8f);
  int rq = 0, rp = 0;
  rq = __builtin_amdgcn_cvt_pk_fp8_f32(qv.x * invq, qv.y * invq, rq, false);
  rq = __builtin_amdgcn_cvt_pk_fp8_f32(qv.z * invq, qv.w * invq, rq, true);
  rp = __builtin_amdgcn_cvt_pk_fp8_f32(pv.x * invp, pv.y * invp, rp, false);
  rp = __builtin_amdgcn_cvt_pk_fp8_f32(pv.z * invp, pv.w * invp, rp, true);
  qh[i * 128 + t] = (unsigned int)rq;
  ph[i * 128 + t] = (unsigned int)rp;
  if (t == 0) diag[i] = dt * invq * invp * 20.0f;
}

// ---------- Phase 2: persistent MX-fp8 GEMM, TRANSPOSED accumulators ----------
// r13 champion (L2-resident XCD map, 61->59us) with ONE change: MFMA operands
// swapped (acc = mfma(bf, af) = C^T). D-layout (shape-determined): lane holds
// row m = l15 (FIXED), cols n = l4*4+r. Row-sum becomes 16 reg-adds +
// 2 shuffles (xor16,32) + 1 predicated psum write per am — 8x fewer LDS-pipe
// ops in the epilogue (128->16 bpermutes/wave/flush), kills the 3.1M bank
// conflicts. A/B fragment layouts for 16x16x128 are symmetric so operand
// swap is legal; both formats fp8, both scales 1.0.
__device__ __forceinline__ i32x8 rd32(const char* base, int c0, int sw) {
  const i32x4 lo = *(const i32x4*)(base + ((c0     ) ^ sw));
  const i32x4 hi = *(const i32x4*)(base + ((c0 + 16) ^ sw));
  return __builtin_shufflevector(lo, hi, 0, 1, 2, 3, 4, 5, 6, 7);
}
__device__ __forceinline__ void stage_half(const char* __restrict__ g, char* dstb,
                                           int rowbase, int h, int tid, int kb) {
  #pragma unroll
  for (int j = 0; j < 2; ++j) {
    const int idx = j * 512 + tid;
    const int rl = idx >> 3;
    const int scb = ((idx & 7) << 4) ^ ((rl & 7) << 4);
    gld_lds16(g + (size_t)(rowbase + h * 128 + rl) * 512 + kb + scb,
              dstb + h * 16384 + idx * 16);
  }
}

// acc[nb][am]: nb = QB*2+nf (col-frag), am = QA*4+mf (row-frag). D = C^T.
#define MFMA_Q(AF, BF, QA, QB)                                                \
  __builtin_amdgcn_s_setprio(1);                                              \
  _Pragma("unroll") for (int mf = 0; mf < 4; ++mf)                            \
    _Pragma("unroll") for (int nf = 0; nf < 2; ++nf)                          \
      acc[QB * 2 + nf][QA * 4 + mf] =                                         \
          __builtin_amdgcn_mfma_scale_f32_16x16x128_f8f6f4(                   \
              BF[nf], AF[mf], acc[QB * 2 + nf][QA * 4 + mf], 0, 0,            \
              0, FP8_SCALE_1, 0, FP8_SCALE_1);                                \
  __builtin_amdgcn_s_setprio(0);

__global__ __launch_bounds__(512, 2) void gemm_lse_k(
    const unsigned int* __restrict__ qh, const unsigned int* __restrict__ ph,
    float* __restrict__ partial) {
  __shared__ __attribute__((aligned(16))) char lds[135168];  // 2x64KB + 4KB psum
  const int tid = threadIdx.x;
  const int lane = tid & 63, wid = tid >> 6;
  const int wr = wid >> 2, wc = wid & 3;
  const int l15 = lane & 15, l4 = lane >> 4;
  const int sw = (l15 & 7) << 4;
  const int c0 = l4 * 32;
  const int b = blockIdx.x;
  const int g = b & 7;                    // XCD (round-robin dispatch)
  const int j = b >> 3;                   // 0..31 within XCD
  const int rowgrp = g & 3, colgrp = g >> 2;
  const int bm = (rowgrp * 8 + (j & 7)) * BM;        // A panel (4 blocks share)
  const int bnset = colgrp * 16 + (j >> 3) * 4;      // 4 bn panels (8 share)
  const char* qh8 = (const char*)qh;
  const char* ph8 = (const char*)ph;
  float* psum = (float*)(lds + 131072);
  const int aOff = wr * 16384 + l15 * 128;
  const int bOff = 32768 + (wc >> 1) * 16384 +
                   ((wc & 1) * 64 + l15) * 128;

  f32x4 acc[4][8] = {};
  i32x8 af0[4], af1[4], bf0[2], bf1[2];

  // Prologue: stage tile 0 (bn = bnset, k-tile 0), drain, barrier.
  {
    const int bn0 = bnset * BN;
    stage_half(qh8, lds, bm, 0, tid, 0);
    stage_half(ph8, lds + 32768, bn0, 0, tid, 0);
    stage_half(ph8, lds + 32768, bn0, 1, tid, 0);
    stage_half(qh8, lds, bm, 1, tid, 0);
    asm volatile("s_waitcnt vmcnt(0)" ::: "memory");
    __builtin_amdgcn_s_barrier();
  }

  #pragma unroll 1
  for (int tt = 0; tt < 16; ++tt) {
    const char* rb = lds + (tt & 1) * 65536;
    char* sbA = lds + ((tt + 1) & 1) * 65536;
    char* sbB = sbA + 32768;
    const int ttn = tt + 1;
    const int kbn = (ttn & 3) * 128;                     // next K-tile byte offset
    const int bnn = (bnset + ((ttn >> 2) & 3)) * BN;     // next tile's bn
    const bool st = (tt < 15);

    // front-load reads (16 + 8 ds_read_b128)
    #pragma unroll
    for (int mf = 0; mf < 4; ++mf)
      af0[mf] = rd32(rb + aOff + mf * 2048, c0, sw);
    #pragma unroll
    for (int nf = 0; nf < 2; ++nf)
      bf0[nf] = rd32(rb + bOff + nf * 2048, c0, sw);
    #pragma unroll
    for (int nf = 0; nf < 2; ++nf)
      bf1[nf] = rd32(rb + bOff + 4096 + nf * 2048, c0, sw);
    if (st) {
      stage_half(qh8, sbA, bm, 0, tid, kbn);
      stage_half(ph8, sbB, bnn, 0, tid, kbn);
    }
    MFMA_Q(af0, bf0, 0, 0);
    #pragma unroll
    for (int mf = 0; mf < 4; ++mf)
      af1[mf] = rd32(rb + aOff + 8192 + mf * 2048, c0, sw);
    MFMA_Q(af0, bf1, 0, 1);
    if (st) {
      stage_half(ph8, sbB, bnn, 1, tid, kbn);
      stage_half(qh8, sbA, bm, 1, tid, kbn);
    }
    MFMA_Q(af1, bf1, 1, 1);
    MFMA_Q(af1, bf0, 1, 0);

    asm volatile("s_waitcnt vmcnt(0)" ::: "memory");  // stages landed (issued early)
    __builtin_amdgcn_s_barrier();

    if ((tt & 3) == 3) {
      // ---- flush output tile (tt>>2): exp(20c-20) + row-sum + store ----
      // Lane holds rows m = wr*128 + am*16 + l15; cols n = wc*64+nb*16+l4*4+r.
      const int bxc = bnset + (tt >> 2);
      #pragma unroll
      for (int am = 0; am < 8; ++am) {
        float s = 0.0f;
        #pragma unroll
        for (int nb = 0; nb < 4; ++nb)
          #pragma unroll
          for (int r = 0; r < 4; ++r)
            s += __expf(acc[nb][am][r] * 20.0f - 20.0f);
        s += __shfl_xor(s, 16, 64);
        s += __shfl_xor(s, 32, 64);
        if (l4 == 0)
          psum[wc * 256 + wr * 128 + am * 16 + l15] = s;
      }
      asm volatile("s_waitcnt lgkmcnt(0)" ::: "memory");
      __builtin_amdgcn_s_barrier();
      if (tid < 256) {
        float s = psum[tid] + psum[256 + tid] + psum[512 + tid] + psum[768 + tid];
        partial[(size_t)(bm + tid) * 32 + bxc] = s;
      }
      #pragma unroll
      for (int nb = 0; nb < 4; ++nb)
        #pragma unroll
        for (int am = 0; am < 8; ++am)
          acc[nb][am] = f32x4{0.0f, 0.0f, 0.0f, 0.0f};
    }
  }
}

// ---------- Phase 3a: per-row loss ----------
__global__ __launch_bounds__(256) void rowloss_k(
    const float* __restrict__ partial, const float* __restrict__ diag,
    float* __restrict__ rowloss) {
  const int i = blockIdx.x * 256 + threadIdx.x;
  const float4* pr = (const float4*)(partial + (size_t)i * 32);
  float s = 0.0f;
  #pragma unroll
  for (int c = 0; c < 8; ++c) {
    const float4 v = pr[c];
    s += v.x + v.y + v.z + v.w;
  }
  rowloss[i] = __logf(s) + 20.0f - diag[i];
}

// ---------- Phase 3b: mean ----------
__global__ __launch_bounds__(1024) void final_k(
    const float* __restrict__ rowloss, float* __restrict__ out) {
  const int t = threadIdx.x;
  float s = 0.0f;
  #pragma unroll
  for (int j = 0; j < 8; ++j) s += rowloss[t + j * 1024];
  #pragma unroll
  for (int m = 1; m < 64; m <<= 1) s += __shfl_xor(s, m, 64);
  __shared__ float red[16];
  if ((t & 63) == 0) red[t >> 6] = s;
  __syncthreads();
  if (t == 0) {
    float acc = 0.0f;
    #pragma unroll
    for (int w = 0; w < 16; ++w) acc += red[w];
    out[0] = acc * (1.0f / (float)NROWS);
  }
}

extern "C" void kernel_launch(void* const* d_in, const int* in_sizes, int n_in,
                              void* d_out, int out_size, void* d_ws, size_t ws_size,
                              hipStream_t stream) {
  const float* q = (const float*)d_in[0];
  const float* p = (const float*)d_in[1];
  char* w = (char*)d_ws;
  unsigned int* qh = (unsigned int*)w;                        // 4 MB fp8
  unsigned int* ph = (unsigned int*)(w + 4194304);            // 4 MB fp8
  float* partial    = (float*)(w + 8388608);                  // 1 MB [8192][32]
  float* diag       = (float*)(w + 9437184);                  // 32 KB
  float* rowloss    = (float*)(w + 9437184 + 32768);          // 32 KB
  float* out = (float*)d_out;

  prep_k<<<NROWS, 128, 0, stream>>>(q, p, qh, ph, diag);
  gemm_lse_k<<<256, 512, 0, stream>>>(qh, ph, partial);
  rowloss_k<<<NROWS / 256, 256, 0, stream>>>(partial, diag, rowloss);
  final_k<<<1, 1024, 0, stream>>>(rowloss, out);
}